// Round 4
// baseline (1146.316 us; speedup 1.0000x reference)
//
#include <hip/hip_runtime.h>

#define B_ 256
#define D_ 128
#define T_ 1024
#define H_ 64
#define G_ 192
#define TILE_T 64
#define NTILES (T_ / TILE_T)   // 16
#define XGS 65                 // t-stride (65 % 32 = 1 -> 2-way max, free)

typedef float f32x4 __attribute__((ext_vector_type(4)));

// Fully fused GRU: one block per batch row, 4 waves.
//   wave 0   : sequential scan, single-wave (no s_barrier in steady state)
//   waves 1-3: GEMM producers, xg tiles -> LDS ring (double buffer)
// Sync via LDS atomic counters (workgroup scope).
// KEY (round-4 fix): W_hh weights (192 VGPRs) are laundered through opaque
// asm so the compiler CANNOT rematerialize the loads inside the scan loop
// (round 3: VGPR_Count=132 < 192 -> weights re-loaded from global every
// step -> ~3000 cyc/step).
__global__ __launch_bounds__(256, 1) void gru_fused(
    const float* __restrict__ lat, const float* __restrict__ hidden_init,
    const float* __restrict__ W_ih, const float* __restrict__ W_hh,
    const float* __restrict__ b_ih, const float* __restrict__ b_hh,
    const float* __restrict__ head_w, const float* __restrict__ head_b,
    float* __restrict__ out)
{
    __shared__ float xg_s[2][G_ * XGS];   // [slot][g*XGS + t]  (97.5 KB)
    __shared__ float h_lds[H_];
    __shared__ unsigned prod_done[2];
    __shared__ unsigned cons_done[2];

    const int b    = blockIdx.x;
    const int tid  = threadIdx.x;
    const int lane = tid & 63;
    const int wid  = __builtin_amdgcn_readfirstlane(tid >> 6);

    if (tid < 2) { prod_done[tid] = 0u; cons_done[tid] = 0u; }
    __syncthreads();   // the ONLY workgroup barrier (all 4 waves present)

    if (wid == 0) {
        // ------------------------- consumer: the scan -------------------------
        const int j = lane;
        f32x4 wr4[16], wz4[16], wn4[16];
        {
            const f32x4* Wr = (const f32x4*)(W_hh + (size_t)j * H_);
            const f32x4* Wz = (const f32x4*)(W_hh + (size_t)(H_ + j) * H_);
            const f32x4* Wn = (const f32x4*)(W_hh + (size_t)(2 * H_ + j) * H_);
#pragma unroll
            for (int q = 0; q < 16; ++q) { wr4[q] = Wr[q]; wz4[q] = Wz[q]; wn4[q] = Wn[q]; }
        }
        // Opaque laundering: forces the 192 weight values to stay VGPR-resident
        // (asm volatile results cannot be rematerialized by reloading).
#pragma unroll
        for (int q = 0; q < 16; ++q) {
            asm volatile("" : "+v"(wr4[q]), "+v"(wz4[q]), "+v"(wn4[q]));
        }
        const float br = b_hh[j], bz = b_hh[H_ + j], bn = b_hh[2 * H_ + j];
        const float hw = head_w[j];
        float h = hidden_init[b * H_ + j];

        for (int k = 0; k < NTILES; ++k) {
            const int s = k & 1;
            const unsigned tgt = 3u * (unsigned)((k >> 1) + 1);
            while (__hip_atomic_load(&prod_done[s], __ATOMIC_ACQUIRE,
                                     __HIP_MEMORY_SCOPE_WORKGROUP) < tgt)
                __builtin_amdgcn_s_sleep(1);

            const float* xrp = &xg_s[s][(size_t)j * XGS];
            const float* xzp = &xg_s[s][(size_t)(H_ + j) * XGS];
            const float* xnp = &xg_s[s][(size_t)(2 * H_ + j) * XGS];

#pragma unroll 2
            for (int t = 0; t < TILE_T; ++t) {
                float xr = xrp[t];
                float xz = xzp[t];
                float xn = xnp[t];

                h_lds[j] = h;                       // within-wave: DS in-order
                const f32x4* h4 = (const f32x4*)h_lds;
                float ar = 0.f, az = 0.f, an = 0.f;
#pragma unroll
                for (int q = 0; q < 16; ++q) {
                    f32x4 hv = h4[q];               // broadcast read (free)
                    ar = fmaf(wr4[q].x, hv.x, ar); ar = fmaf(wr4[q].y, hv.y, ar);
                    ar = fmaf(wr4[q].z, hv.z, ar); ar = fmaf(wr4[q].w, hv.w, ar);
                    az = fmaf(wz4[q].x, hv.x, az); az = fmaf(wz4[q].y, hv.y, az);
                    az = fmaf(wz4[q].z, hv.z, az); az = fmaf(wz4[q].w, hv.w, az);
                    an = fmaf(wn4[q].x, hv.x, an); an = fmaf(wn4[q].y, hv.y, an);
                    an = fmaf(wn4[q].z, hv.z, an); an = fmaf(wn4[q].w, hv.w, an);
                }
                float r  = __builtin_amdgcn_rcpf(1.f + __expf(-(xr + ar + br)));
                float z  = __builtin_amdgcn_rcpf(1.f + __expf(-(xz + az + bz)));
                float pre = xn + r * (an + bn);
                // tanh(pre) = 1 - 2/(e^{2x}+1); inf/0 limits give +/-1 correctly
                float n  = fmaf(-2.f, __builtin_amdgcn_rcpf(__expf(2.f * pre) + 1.f), 1.f);
                h = (1.f - z) * n + z * h;
            }
            if (lane == 0)
                __hip_atomic_fetch_add(&cons_done[s], 1u, __ATOMIC_RELEASE,
                                       __HIP_MEMORY_SCOPE_WORKGROUP);
        }

        // epilogue: final hidden + head
        out[B_ + b * H_ + j] = h;
        float v = h * hw;
#pragma unroll
        for (int off = 32; off > 0; off >>= 1) v += __shfl_down(v, off);
        if (lane == 0) out[b] = v + head_b[0];
    } else {
        // ----------------------- producers: xg GEMM tiles ----------------------
        const int gw = (wid - 1) * 64;              // this wave's 64 gates
        const float* latb = lat + (size_t)b * (D_ * T_);

        for (int k = 0; k < NTILES; ++k) {
            const int s = k & 1, m = k >> 1;
            if (m >= 1) {
                while (__hip_atomic_load(&cons_done[s], __ATOMIC_ACQUIRE,
                                         __HIP_MEMORY_SCOPE_WORKGROUP) < (unsigned)m)
                    __builtin_amdgcn_s_sleep(1);
            }

            float acc[64];
#pragma unroll
            for (int g = 0; g < 64; ++g) acc[g] = b_ih[gw + g];   // uniform s_load

            const float* latt = latb + k * TILE_T + lane;
            for (int d0 = 0; d0 < D_; d0 += 8) {
                float lv[8];
#pragma unroll
                for (int i = 0; i < 8; ++i) lv[i] = latt[(size_t)(d0 + i) * T_];
#pragma unroll
                for (int g = 0; g < 64; ++g) {
                    const float* wrow = W_ih + (size_t)(gw + g) * D_ + d0;  // uniform
#pragma unroll
                    for (int i = 0; i < 8; ++i)
                        acc[g] = fmaf(lv[i], wrow[i], acc[g]);
                }
            }

            float* xs = xg_s[s];
#pragma unroll
            for (int g = 0; g < 64; ++g)
                xs[(size_t)(gw + g) * XGS + lane] = acc[g];   // 2-way: free
            if (lane == 0)
                __hip_atomic_fetch_add(&prod_done[s], 1u, __ATOMIC_RELEASE,
                                       __HIP_MEMORY_SCOPE_WORKGROUP);
        }
    }
}

extern "C" void kernel_launch(void* const* d_in, const int* in_sizes, int n_in,
                              void* d_out, int out_size, void* d_ws, size_t ws_size,
                              hipStream_t stream)
{
    const float* lat   = (const float*)d_in[0];
    const float* hid0  = (const float*)d_in[1];
    const float* W_ih  = (const float*)d_in[2];
    const float* W_hh  = (const float*)d_in[3];
    const float* b_ih  = (const float*)d_in[4];
    const float* b_hh  = (const float*)d_in[5];
    const float* headw = (const float*)d_in[6];
    const float* headb = (const float*)d_in[7];
    float* out = (float*)d_out;

    gru_fused<<<dim3(B_), dim3(256), 0, stream>>>(
        lat, hid0, W_ih, W_hh, b_ih, b_hh, headw, headb, out);
}

// Round 5
// 1143.777 us; speedup vs baseline: 1.0022x; 1.0022x over previous
//
#include <hip/hip_runtime.h>

#define B_ 256
#define D_ 128
#define T_ 1024
#define H_ 64
#define G_ 192
#define TILE_T 64
#define NTILES (T_ / TILE_T)   // 16
#define XGS 65                 // t-stride (65 % 32 = 1 -> 2-way max, free)

typedef float f32x4 __attribute__((ext_vector_type(4)));

// Fully fused GRU: one block per batch row, 4 waves.
//   wave 0   : sequential scan, single-wave (no s_barrier in steady state)
//   waves 1-3: GEMM producers, xg tiles -> LDS ring (double buffer)
// Sync via LDS atomic counters (workgroup scope).
//
// Round-5 fix: amdgpu_waves_per_eu(1,1). LDS (100 KB) already caps us at
// 1 block/CU = 1 wave/EU, but the register allocator doesn't know that:
// with only a min-waves hint it targets ~4 waves/EU (~128 VGPR) and spills
// the 192 W_hh weights to scratch, reloading them EVERY step (~2300
// cyc/step of exposed latency; rounds 3-4 measured 2984 cyc/step at
// VGPR_Count=132). max=1 tells the allocator the true budget (512).
__global__ __attribute__((amdgpu_waves_per_eu(1, 1))) __launch_bounds__(256)
void gru_fused(
    const float* __restrict__ lat, const float* __restrict__ hidden_init,
    const float* __restrict__ W_ih, const float* __restrict__ W_hh,
    const float* __restrict__ b_ih, const float* __restrict__ b_hh,
    const float* __restrict__ head_w, const float* __restrict__ head_b,
    float* __restrict__ out)
{
    __shared__ float xg_s[2][G_ * XGS];   // [slot][g*XGS + t]  (97.5 KB)
    __shared__ float h_lds[H_];
    __shared__ unsigned prod_done[2];
    __shared__ unsigned cons_done[2];

    const int b    = blockIdx.x;
    const int tid  = threadIdx.x;
    const int lane = tid & 63;
    const int wid  = __builtin_amdgcn_readfirstlane(tid >> 6);

    if (tid < 2) { prod_done[tid] = 0u; cons_done[tid] = 0u; }
    __syncthreads();   // the ONLY workgroup barrier (all 4 waves present)

    if (wid == 0) {
        // ------------------------- consumer: the scan -------------------------
        const int j = lane;
        f32x4 wr4[16], wz4[16], wn4[16];
        {
            const f32x4* Wr = (const f32x4*)(W_hh + (size_t)j * H_);
            const f32x4* Wz = (const f32x4*)(W_hh + (size_t)(H_ + j) * H_);
            const f32x4* Wn = (const f32x4*)(W_hh + (size_t)(2 * H_ + j) * H_);
#pragma unroll
            for (int q = 0; q < 16; ++q) { wr4[q] = Wr[q]; wz4[q] = Wz[q]; wn4[q] = Wn[q]; }
        }
        // Prevent rematerialization of the weight loads (spill is prevented by
        // the 512-reg budget from waves_per_eu(1,1)).
#pragma unroll
        for (int q = 0; q < 16; ++q) {
            asm volatile("" : "+v"(wr4[q]), "+v"(wz4[q]), "+v"(wn4[q]));
        }
        const float br = b_hh[j], bz = b_hh[H_ + j], bn = b_hh[2 * H_ + j];
        const float hw = head_w[j];
        float h = hidden_init[b * H_ + j];

        for (int k = 0; k < NTILES; ++k) {
            const int s = k & 1;
            const unsigned tgt = 3u * (unsigned)((k >> 1) + 1);
            while (__hip_atomic_load(&prod_done[s], __ATOMIC_ACQUIRE,
                                     __HIP_MEMORY_SCOPE_WORKGROUP) < tgt)
                __builtin_amdgcn_s_sleep(1);

            const float* xrp = &xg_s[s][(size_t)j * XGS];
            const float* xzp = &xg_s[s][(size_t)(H_ + j) * XGS];
            const float* xnp = &xg_s[s][(size_t)(2 * H_ + j) * XGS];

#pragma unroll 2
            for (int t = 0; t < TILE_T; ++t) {
                float xr = xrp[t];
                float xz = xzp[t];
                float xn = xnp[t];

                h_lds[j] = h;                       // within-wave: DS in-order
                const f32x4* h4 = (const f32x4*)h_lds;
                float ar = 0.f, az = 0.f, an = 0.f;
#pragma unroll
                for (int q = 0; q < 16; ++q) {
                    f32x4 hv = h4[q];               // broadcast read (free)
                    ar = fmaf(wr4[q].x, hv.x, ar); ar = fmaf(wr4[q].y, hv.y, ar);
                    ar = fmaf(wr4[q].z, hv.z, ar); ar = fmaf(wr4[q].w, hv.w, ar);
                    az = fmaf(wz4[q].x, hv.x, az); az = fmaf(wz4[q].y, hv.y, az);
                    az = fmaf(wz4[q].z, hv.z, az); az = fmaf(wz4[q].w, hv.w, az);
                    an = fmaf(wn4[q].x, hv.x, an); an = fmaf(wn4[q].y, hv.y, an);
                    an = fmaf(wn4[q].w, hv.w, an); an = fmaf(wn4[q].z, hv.z, an);
                }
                float r  = __builtin_amdgcn_rcpf(1.f + __expf(-(xr + ar + br)));
                float z  = __builtin_amdgcn_rcpf(1.f + __expf(-(xz + az + bz)));
                float pre = xn + r * (an + bn);
                // tanh(pre) = 1 - 2/(e^{2x}+1); inf/0 limits give +/-1 correctly
                float n  = fmaf(-2.f, __builtin_amdgcn_rcpf(__expf(2.f * pre) + 1.f), 1.f);
                h = (1.f - z) * n + z * h;
            }
            if (lane == 0)
                __hip_atomic_fetch_add(&cons_done[s], 1u, __ATOMIC_RELEASE,
                                       __HIP_MEMORY_SCOPE_WORKGROUP);
        }

        // epilogue: final hidden + head
        out[B_ + b * H_ + j] = h;
        float v = h * hw;
#pragma unroll
        for (int off = 32; off > 0; off >>= 1) v += __shfl_down(v, off);
        if (lane == 0) out[b] = v + head_b[0];
    } else {
        // ----------------------- producers: xg GEMM tiles ----------------------
        const int gw = (wid - 1) * 64;              // this wave's 64 gates
        const float* latb = lat + (size_t)b * (D_ * T_);

        for (int k = 0; k < NTILES; ++k) {
            const int s = k & 1, m = k >> 1;
            if (m >= 1) {
                while (__hip_atomic_load(&cons_done[s], __ATOMIC_ACQUIRE,
                                         __HIP_MEMORY_SCOPE_WORKGROUP) < (unsigned)m)
                    __builtin_amdgcn_s_sleep(1);
            }

            float acc[64];
#pragma unroll
            for (int g = 0; g < 64; ++g) acc[g] = b_ih[gw + g];   // uniform s_load

            const float* latt = latb + k * TILE_T + lane;
            for (int d0 = 0; d0 < D_; d0 += 8) {
                float lv[8];
#pragma unroll
                for (int i = 0; i < 8; ++i) lv[i] = latt[(size_t)(d0 + i) * T_];
#pragma unroll
                for (int g = 0; g < 64; ++g) {
                    const float* wrow = W_ih + (size_t)(gw + g) * D_ + d0;  // uniform
#pragma unroll
                    for (int i = 0; i < 8; ++i)
                        acc[g] = fmaf(lv[i], wrow[i], acc[g]);
                }
            }

            float* xs = xg_s[s];
#pragma unroll
            for (int g = 0; g < 64; ++g)
                xs[(size_t)(gw + g) * XGS + lane] = acc[g];   // 2-way: free
            if (lane == 0)
                __hip_atomic_fetch_add(&prod_done[s], 1u, __ATOMIC_RELEASE,
                                       __HIP_MEMORY_SCOPE_WORKGROUP);
        }
    }
}

extern "C" void kernel_launch(void* const* d_in, const int* in_sizes, int n_in,
                              void* d_out, int out_size, void* d_ws, size_t ws_size,
                              hipStream_t stream)
{
    const float* lat   = (const float*)d_in[0];
    const float* hid0  = (const float*)d_in[1];
    const float* W_ih  = (const float*)d_in[2];
    const float* W_hh  = (const float*)d_in[3];
    const float* b_ih  = (const float*)d_in[4];
    const float* b_hh  = (const float*)d_in[5];
    const float* headw = (const float*)d_in[6];
    const float* headb = (const float*)d_in[7];
    float* out = (float*)d_out;

    gru_fused<<<dim3(B_), dim3(256), 0, stream>>>(
        lat, hid0, W_ih, W_hh, b_ih, b_hh, headw, headb, out);
}

// Round 6
// 764.242 us; speedup vs baseline: 1.4999x; 1.4966x over previous
//
#include <hip/hip_runtime.h>

#define B_ 256
#define D_ 128
#define T_ 1024
#define H_ 64
#define G_ 192
#define TILE_T 64
#define NTILES (T_ / TILE_T)   // 16
#define XGS 65                 // ring t-stride: 65%32=1 -> 2-way max (free)
#define KC 32                  // producer k-chunk
#define WS 194                 // w_s g-stride: even (8B align), 194%32=2 -> 2-way

typedef float f32x4 __attribute__((ext_vector_type(4)));

// Fused GRU, 1 launch. Block = 1 batch row, 7 waves (448 thr), 1 block/CU.
//   waves 0,1,2 : scan, one GATE each (r,z,n). 64 weight VGPRs/lane -> no
//                 spill pressure (rounds 3-5: 1 wave needed 192 -> allocator
//                 spilled at VGPR=132 and producers were ALSO the wall).
//   waves 3..6  : round-2-style register-tiled GEMM producers -> LDS ring.
// All sync via LDS atomics; s_barrier only once at start.
__global__ __launch_bounds__(448, 2) void gru_fused(
    const float* __restrict__ lat, const float* __restrict__ hidden_init,
    const float* __restrict__ W_ih, const float* __restrict__ W_hh,
    const float* __restrict__ b_ih, const float* __restrict__ b_hh,
    const float* __restrict__ head_w, const float* __restrict__ head_b,
    float* __restrict__ out)
{
    __shared__ float xg_s[2][G_ * XGS];     // 99,840 B ring [slot][g*XGS+t]
    __shared__ float lat_s[D_ * TILE_T];    // 32,768 B [d][t]
    __shared__ float w_s[KC * WS];          // 24,832 B [kk][g]
    __shared__ float h_s[H_], r_s[H_], n_s[H_];
    __shared__ unsigned prod_done[2], cons_done[2], A_r, A_n, A_h, pbar;

    const int b    = blockIdx.x;
    const int tid  = threadIdx.x;
    const int lane = tid & 63;
    const int wid  = tid >> 6;

    if (tid < 2) { prod_done[tid] = 0u; cons_done[tid] = 0u; }
    if (tid == 2) { A_r = 0u; A_n = 0u; A_h = 0u; pbar = 0u; }
    if (tid < H_) h_s[tid] = hidden_init[b * H_ + tid];
    __syncthreads();   // only workgroup barrier (all 7 waves present)

    if (wid < 3) {
        // ===================== scan: one gate per wave =====================
        const int j   = lane;
        const int row = wid * H_ + j;        // 0..63 r | 64..127 z | 128..191 n
        f32x4 w4[16];
        {
            const f32x4* W = (const f32x4*)(W_hh + (size_t)row * H_);
#pragma unroll
            for (int q = 0; q < 16; ++q) w4[q] = W[q];
        }
        asm volatile("" : "+v"(w4[0]), "+v"(w4[1]), "+v"(w4[2]), "+v"(w4[3]),
                          "+v"(w4[4]), "+v"(w4[5]), "+v"(w4[6]), "+v"(w4[7]),
                          "+v"(w4[8]), "+v"(w4[9]), "+v"(w4[10]), "+v"(w4[11]),
                          "+v"(w4[12]), "+v"(w4[13]), "+v"(w4[14]), "+v"(w4[15]));
        const float bias = b_hh[row];
        const float hw   = (wid == 1) ? head_w[j] : 0.f;
        float hlast = 0.f;
        unsigned sg = 0;

        for (int k = 0; k < NTILES; ++k) {
            const int s = k & 1;
            const unsigned tgt = 4u * (unsigned)((k >> 1) + 1);
            while (__hip_atomic_load(&prod_done[s], __ATOMIC_ACQUIRE,
                                     __HIP_MEMORY_SCOPE_WORKGROUP) < tgt)
                __builtin_amdgcn_s_sleep(1);
            const float* xrow = &xg_s[s][(size_t)row * XGS];

            for (int t = 0; t < TILE_T; ++t, ++sg) {
                // h for step sg ready when A_h >= sg
                while (__hip_atomic_load(&A_h, __ATOMIC_ACQUIRE,
                                         __HIP_MEMORY_SCOPE_WORKGROUP) < sg) {}
                const float xv = xrow[t];
                const f32x4* h4 = (const f32x4*)h_s;
                float a = bias;
#pragma unroll
                for (int q = 0; q < 16; ++q) {
                    f32x4 hv = h4[q];           // broadcast read
                    a = fmaf(w4[q].x, hv.x, a); a = fmaf(w4[q].y, hv.y, a);
                    a = fmaf(w4[q].z, hv.z, a); a = fmaf(w4[q].w, hv.w, a);
                }
                if (wid == 0) {          // r gate
                    float r = __builtin_amdgcn_rcpf(1.f + __expf(-(xv + a)));
                    r_s[j] = r;
                    if (lane == 0)
                        __hip_atomic_fetch_add(&A_r, 1u, __ATOMIC_RELEASE,
                                               __HIP_MEMORY_SCOPE_WORKGROUP);
                } else if (wid == 2) {   // n gate: needs r
                    while (__hip_atomic_load(&A_r, __ATOMIC_ACQUIRE,
                                             __HIP_MEMORY_SCOPE_WORKGROUP) < sg + 1) {}
                    float r   = r_s[j];
                    float pre = xv + r * a;   // a = hn (dot + bias)
                    float n   = fmaf(-2.f, __builtin_amdgcn_rcpf(__expf(2.f * pre) + 1.f), 1.f);
                    n_s[j] = n;
                    if (lane == 0)
                        __hip_atomic_fetch_add(&A_n, 1u, __ATOMIC_RELEASE,
                                               __HIP_MEMORY_SCOPE_WORKGROUP);
                } else {                 // z gate: needs n, updates h
                    float z = __builtin_amdgcn_rcpf(1.f + __expf(-(xv + a)));
                    while (__hip_atomic_load(&A_n, __ATOMIC_ACQUIRE,
                                             __HIP_MEMORY_SCOPE_WORKGROUP) < sg + 1) {}
                    float n    = n_s[j];
                    float hj   = h_s[j];
                    float hnew = (1.f - z) * n + z * hj;
                    h_s[j] = hnew;
                    hlast  = hnew;
                    if (lane == 0)
                        __hip_atomic_fetch_add(&A_h, 1u, __ATOMIC_RELEASE,
                                               __HIP_MEMORY_SCOPE_WORKGROUP);
                }
            }
            if (wid == 1 && lane == 0)   // z wave is last in chain: ring free
                __hip_atomic_fetch_add(&cons_done[s], 1u, __ATOMIC_RELEASE,
                                       __HIP_MEMORY_SCOPE_WORKGROUP);
        }

        if (wid == 1) {   // z wave holds final h per lane
            out[B_ + b * H_ + j] = hlast;
            float v = hlast * hw;
#pragma unroll
            for (int off = 32; off > 0; off >>= 1) v += __shfl_down(v, off);
            if (lane == 0) out[b] = v + head_b[0];
        }
    } else {
        // ================= producers: register-tiled GEMM =================
        const int p  = tid - 192;        // 0..255
        const int tx = p & 7;            // t-sub: t = tx*8 + j
        const int gy = p >> 3;           // g-sub: g = gy*6 + i  (32 groups)
        const float* latb = lat + (size_t)b * (D_ * T_);
        unsigned phase = 0;

        auto psync = [&]() {
            if ((p & 63) == 0)
                __hip_atomic_fetch_add(&pbar, 1u, __ATOMIC_RELEASE,
                                       __HIP_MEMORY_SCOPE_WORKGROUP);
            ++phase;
            while (__hip_atomic_load(&pbar, __ATOMIC_ACQUIRE,
                                     __HIP_MEMORY_SCOPE_WORKGROUP) < 4u * phase) {}
        };

        float bias[6];
#pragma unroll
        for (int i = 0; i < 6; ++i) bias[i] = b_ih[gy * 6 + i];

        for (int k = 0; k < NTILES; ++k) {
            const int s = k & 1, m = k >> 1;
            if (m >= 1) {
                while (__hip_atomic_load(&cons_done[s], __ATOMIC_ACQUIRE,
                                         __HIP_MEMORY_SCOPE_WORKGROUP) < (unsigned)m)
                    __builtin_amdgcn_s_sleep(1);
            }
            psync();   // all producers done with previous tile's lat_s/w_s

            // stage lat tile [d][t] (coalesced)
#pragma unroll
            for (int i = 0; i < 32; ++i) {
                int f = p + 256 * i;           // f = d*64 + t
                int d = f >> 6, t = f & 63;
                lat_s[f] = latb[(size_t)d * T_ + k * TILE_T + t];
            }

            float acc[8][6];
#pragma unroll
            for (int jj = 0; jj < 8; ++jj)
#pragma unroll
                for (int i = 0; i < 6; ++i) acc[jj][i] = 0.f;

            for (int kc = 0; kc < D_; kc += KC) {
                psync();   // lat_s staged (k==0 case) / previous w_s consumed
#pragma unroll
                for (int i = 0; i < (G_ * KC) / 256; ++i) {   // 24/thread
                    int f = p + 256 * i;
                    int g = f >> 5, kk = f & 31;
                    w_s[kk * WS + g] = W_ih[(size_t)g * D_ + kc + kk];
                }
                psync();   // w_s ready
#pragma unroll 4
                for (int kk = 0; kk < KC; ++kk) {
                    f32x4 l0 = *(const f32x4*)&lat_s[(kc + kk) * 64 + tx * 8];
                    f32x4 l1 = *(const f32x4*)&lat_s[(kc + kk) * 64 + tx * 8 + 4];
                    float2 w0 = *(const float2*)&w_s[kk * WS + gy * 6];
                    float2 w1 = *(const float2*)&w_s[kk * WS + gy * 6 + 2];
                    float2 w2 = *(const float2*)&w_s[kk * WS + gy * 6 + 4];
                    float lv[8] = {l0.x, l0.y, l0.z, l0.w, l1.x, l1.y, l1.z, l1.w};
                    float wv[6] = {w0.x, w0.y, w1.x, w1.y, w2.x, w2.y};
#pragma unroll
                    for (int jj = 0; jj < 8; ++jj)
#pragma unroll
                        for (int i = 0; i < 6; ++i)
                            acc[jj][i] = fmaf(lv[jj], wv[i], acc[jj][i]);
                }
            }

            // write tile to ring slot (b32, ~2-way banks)
            float* xs = xg_s[s];
#pragma unroll
            for (int i = 0; i < 6; ++i)
#pragma unroll
                for (int jj = 0; jj < 8; ++jj)
                    xs[(size_t)(gy * 6 + i) * XGS + tx * 8 + jj] = acc[jj][i] + bias[i];

            if ((p & 63) == 0)
                __hip_atomic_fetch_add(&prod_done[s], 1u, __ATOMIC_RELEASE,
                                       __HIP_MEMORY_SCOPE_WORKGROUP);
        }
    }
}

extern "C" void kernel_launch(void* const* d_in, const int* in_sizes, int n_in,
                              void* d_out, int out_size, void* d_ws, size_t ws_size,
                              hipStream_t stream)
{
    const float* lat   = (const float*)d_in[0];
    const float* hid0  = (const float*)d_in[1];
    const float* W_ih  = (const float*)d_in[2];
    const float* W_hh  = (const float*)d_in[3];
    const float* b_ih  = (const float*)d_in[4];
    const float* b_hh  = (const float*)d_in[5];
    const float* headw = (const float*)d_in[6];
    const float* headb = (const float*)d_in[7];
    float* out = (float*)d_out;

    gru_fused<<<dim3(B_), dim3(448), 0, stream>>>(
        lat, hid0, W_ih, W_hh, b_ih, b_hh, headw, headb, out);
}

// Round 7
// 675.452 us; speedup vs baseline: 1.6971x; 1.1315x over previous
//
#include <hip/hip_runtime.h>

#define B_ 256
#define D_ 128
#define T_ 1024
#define H_ 64
#define G_ 192
#define TILE_T 64
#define NTILES (T_ / TILE_T)   // 16
#define XGS 65                 // ring t-stride: 65%32=1 -> 2-way max (free)
#define KC 32                  // producer k-chunk
#define WS 194                 // w_s g-stride

typedef float f32x4 __attribute__((ext_vector_type(4)));
typedef unsigned long long u64;

// Fused GRU, 1 launch. Block = 1 batch row, 7 waves, 1 block/CU.
//   waves 0(r),1(z+h),2(n) : scan, one gate each (64 weight VGPRs -> no spill)
//   waves 3..6             : register-tiled GEMM producers -> LDS ring
// Round-7: data-as-flag b64 handoffs (value+tag in one DS atom) replace
// counter+data hops (~300 -> ~185 cyc); 4-acc dots break the 256-cyc
// dependent FMA chain; s_setprio(1) shields scan waves from producer bursts.
__global__ __launch_bounds__(448, 2) void gru_fused(
    const float* __restrict__ lat, const float* __restrict__ hidden_init,
    const float* __restrict__ W_ih, const float* __restrict__ W_hh,
    const float* __restrict__ b_ih, const float* __restrict__ b_hh,
    const float* __restrict__ head_w, const float* __restrict__ head_b,
    float* __restrict__ out)
{
    __shared__ float xg_s[2][G_ * XGS];     // 99,840 B ring [slot][g*XGS+t]
    __shared__ float lat_s[D_ * TILE_T];    // 32,768 B [d][t]
    __shared__ float w_s[KC * WS];          // 24,832 B [kk][g]
    __shared__ float h_s[H_];
    __shared__ u64  r_slot[H_], n_slot[H_]; // {tag<<32 | bits(value)}
    __shared__ unsigned prod_done[2], cons_done[2], A_h, pbar;

    const int b    = blockIdx.x;
    const int tid  = threadIdx.x;
    const int lane = tid & 63;
    const int wid  = tid >> 6;

    if (tid < 2) { prod_done[tid] = 0u; cons_done[tid] = 0u; }
    if (tid == 2) { A_h = 0u; pbar = 0u; }
    if (tid < H_) { h_s[tid] = hidden_init[b * H_ + tid];
                    r_slot[tid] = 0ull; n_slot[tid] = 0ull; }
    __syncthreads();   // only workgroup barrier (all 7 waves present)

    if (wid < 3) {
        // ===================== scan: one gate per wave =====================
        __builtin_amdgcn_s_setprio(1);      // favor the latency-critical chain
        const int j    = lane;
        const int gate = (wid == 0) ? 0 : (wid == 1) ? 1 : 2;  // r | z | n
        const int row  = gate * H_ + j;
        f32x4 w4[16];
        {
            const f32x4* W = (const f32x4*)(W_hh + (size_t)row * H_);
#pragma unroll
            for (int q = 0; q < 16; ++q) w4[q] = W[q];
        }
        asm volatile("" : "+v"(w4[0]), "+v"(w4[1]), "+v"(w4[2]), "+v"(w4[3]),
                          "+v"(w4[4]), "+v"(w4[5]), "+v"(w4[6]), "+v"(w4[7]),
                          "+v"(w4[8]), "+v"(w4[9]), "+v"(w4[10]), "+v"(w4[11]),
                          "+v"(w4[12]), "+v"(w4[13]), "+v"(w4[14]), "+v"(w4[15]));
        const float bias = b_hh[row];
        const float hw   = (wid == 1) ? head_w[j] : 0.f;
        float hlast = 0.f;
        unsigned sg = 0;

        for (int k = 0; k < NTILES; ++k) {
            const int s = k & 1;
            const unsigned tgt = 4u * (unsigned)((k >> 1) + 1);
            while (__hip_atomic_load(&prod_done[s], __ATOMIC_ACQUIRE,
                                     __HIP_MEMORY_SCOPE_WORKGROUP) < tgt)
                __builtin_amdgcn_s_sleep(1);
            const float* xrow = &xg_s[s][(size_t)row * XGS];
            float xv = xrow[0];

            for (int t = 0; t < TILE_T; ++t, ++sg) {
                float xnext = xrow[t + 1];   // t=63 reads pad (harmless)
                // wait h for step sg
                while (__hip_atomic_load(&A_h, __ATOMIC_ACQUIRE,
                                         __HIP_MEMORY_SCOPE_WORKGROUP) < sg) {}
                const f32x4* h4 = (const f32x4*)h_s;
                float a0 = 0.f, a1 = 0.f, a2 = 0.f, a3 = 0.f;
#pragma unroll
                for (int q = 0; q < 16; ++q) {
                    f32x4 hv = h4[q];           // broadcast read
                    a0 = fmaf(w4[q].x, hv.x, a0); a1 = fmaf(w4[q].y, hv.y, a1);
                    a2 = fmaf(w4[q].z, hv.z, a2); a3 = fmaf(w4[q].w, hv.w, a3);
                }
                float a = ((a0 + a1) + (a2 + a3)) + bias;
                const unsigned want = sg + 1;

                if (wid == 0) {          // r gate -> slot
                    float r = __builtin_amdgcn_rcpf(1.f + __expf(-(xv + a)));
                    u64 pk = ((u64)want << 32) | (u64)__builtin_bit_cast(unsigned, r);
                    __hip_atomic_store(&r_slot[j], pk, __ATOMIC_RELAXED,
                                       __HIP_MEMORY_SCOPE_WORKGROUP);
                } else if (wid == 2) {   // n gate: needs r
                    u64 v;
                    do { v = __hip_atomic_load(&r_slot[j], __ATOMIC_RELAXED,
                                               __HIP_MEMORY_SCOPE_WORKGROUP);
                    } while ((unsigned)(v >> 32) != want);
                    float r   = __builtin_bit_cast(float, (unsigned)v);
                    float pre = xv + r * a;
                    float n   = fmaf(-2.f, __builtin_amdgcn_rcpf(__expf(2.f * pre) + 1.f), 1.f);
                    u64 pk = ((u64)want << 32) | (u64)__builtin_bit_cast(unsigned, n);
                    __hip_atomic_store(&n_slot[j], pk, __ATOMIC_RELAXED,
                                       __HIP_MEMORY_SCOPE_WORKGROUP);
                } else {                 // z gate: needs n, updates h
                    float z  = __builtin_amdgcn_rcpf(1.f + __expf(-(xv + a)));
                    float hj = h_s[j];
                    float zh = z * hj, zc = 1.f - z;
                    u64 v;
                    do { v = __hip_atomic_load(&n_slot[j], __ATOMIC_RELAXED,
                                               __HIP_MEMORY_SCOPE_WORKGROUP);
                    } while ((unsigned)(v >> 32) != want);
                    float n    = __builtin_bit_cast(float, (unsigned)v);
                    float hnew = fmaf(zc, n, zh);
                    h_s[j] = hnew;
                    hlast  = hnew;
                    if (lane == 0)
                        __hip_atomic_fetch_add(&A_h, 1u, __ATOMIC_RELEASE,
                                               __HIP_MEMORY_SCOPE_WORKGROUP);
                }
                xv = xnext;
            }
            if (wid == 1 && lane == 0)   // z wave is last in chain: ring free
                __hip_atomic_fetch_add(&cons_done[s], 1u, __ATOMIC_RELEASE,
                                       __HIP_MEMORY_SCOPE_WORKGROUP);
        }

        if (wid == 1) {   // z wave holds final h per lane
            out[B_ + b * H_ + j] = hlast;
            float v = hlast * hw;
#pragma unroll
            for (int off = 32; off > 0; off >>= 1) v += __shfl_down(v, off);
            if (lane == 0) out[b] = v + head_b[0];
        }
    } else {
        // ================= producers: register-tiled GEMM =================
        const int p  = tid - 192;        // 0..255
        const int tx = p & 7;            // t-sub: t = tx*8 + jj
        const int gy = p >> 3;           // g-sub: g = gy*6 + i
        const float* latb = lat + (size_t)b * (D_ * T_);
        unsigned phase = 0;

        auto psync = [&]() {
            if ((p & 63) == 0)
                __hip_atomic_fetch_add(&pbar, 1u, __ATOMIC_RELEASE,
                                       __HIP_MEMORY_SCOPE_WORKGROUP);
            ++phase;
            while (__hip_atomic_load(&pbar, __ATOMIC_ACQUIRE,
                                     __HIP_MEMORY_SCOPE_WORKGROUP) < 4u * phase) {}
        };

        float bias[6];
#pragma unroll
        for (int i = 0; i < 6; ++i) bias[i] = b_ih[gy * 6 + i];

        for (int k = 0; k < NTILES; ++k) {
            const int s = k & 1, m = k >> 1;
            if (m >= 1) {
                while (__hip_atomic_load(&cons_done[s], __ATOMIC_ACQUIRE,
                                         __HIP_MEMORY_SCOPE_WORKGROUP) < (unsigned)m)
                    __builtin_amdgcn_s_sleep(1);
            }
            psync();   // all producers past previous tile's lat_s/w_s

            // stage lat tile [d][t] (coalesced)
#pragma unroll
            for (int i = 0; i < 32; ++i) {
                int f = p + 256 * i;           // f = d*64 + t
                int d = f >> 6, t = f & 63;
                lat_s[f] = latb[(size_t)d * T_ + k * TILE_T + t];
            }

            float acc[8][6];
#pragma unroll
            for (int jj = 0; jj < 8; ++jj)
#pragma unroll
                for (int i = 0; i < 6; ++i) acc[jj][i] = 0.f;

            for (int kc = 0; kc < D_; kc += KC) {
                psync();   // lat_s staged / previous w_s consumed
#pragma unroll
                for (int i = 0; i < (G_ * KC) / 256; ++i) {   // 24/thread
                    int f = p + 256 * i;
                    int g = f >> 5, kk = f & 31;
                    w_s[kk * WS + g] = W_ih[(size_t)g * D_ + kc + kk];
                }
                psync();   // w_s ready
#pragma unroll 4
                for (int kk = 0; kk < KC; ++kk) {
                    f32x4 l0 = *(const f32x4*)&lat_s[(kc + kk) * 64 + tx * 8];
                    f32x4 l1 = *(const f32x4*)&lat_s[(kc + kk) * 64 + tx * 8 + 4];
                    float2 w0 = *(const float2*)&w_s[kk * WS + gy * 6];
                    float2 w1 = *(const float2*)&w_s[kk * WS + gy * 6 + 2];
                    float2 w2 = *(const float2*)&w_s[kk * WS + gy * 6 + 4];
                    float lv[8] = {l0.x, l0.y, l0.z, l0.w, l1.x, l1.y, l1.z, l1.w};
                    float wv[6] = {w0.x, w0.y, w1.x, w1.y, w2.x, w2.y};
#pragma unroll
                    for (int jj = 0; jj < 8; ++jj)
#pragma unroll
                        for (int i = 0; i < 6; ++i)
                            acc[jj][i] = fmaf(lv[jj], wv[i], acc[jj][i]);
                }
            }

            // write tile to ring slot
            float* xs = xg_s[s];
#pragma unroll
            for (int i = 0; i < 6; ++i)
#pragma unroll
                for (int jj = 0; jj < 8; ++jj)
                    xs[(size_t)(gy * 6 + i) * XGS + tx * 8 + jj] = acc[jj][i] + bias[i];

            if ((p & 63) == 0)
                __hip_atomic_fetch_add(&prod_done[s], 1u, __ATOMIC_RELEASE,
                                       __HIP_MEMORY_SCOPE_WORKGROUP);
        }
    }
}

extern "C" void kernel_launch(void* const* d_in, const int* in_sizes, int n_in,
                              void* d_out, int out_size, void* d_ws, size_t ws_size,
                              hipStream_t stream)
{
    const float* lat   = (const float*)d_in[0];
    const float* hid0  = (const float*)d_in[1];
    const float* W_ih  = (const float*)d_in[2];
    const float* W_hh  = (const float*)d_in[3];
    const float* b_ih  = (const float*)d_in[4];
    const float* b_hh  = (const float*)d_in[5];
    const float* headw = (const float*)d_in[6];
    const float* headb = (const float*)d_in[7];
    float* out = (float*)d_out;

    gru_fused<<<dim3(B_), dim3(448), 0, stream>>>(
        lat, hid0, W_ih, W_hh, b_ih, b_hh, headw, headb, out);
}

// Round 8
// 454.284 us; speedup vs baseline: 2.5233x; 1.4868x over previous
//
#include <hip/hip_runtime.h>

#define B_ 256
#define D_ 128
#define T_ 1024
#define H_ 64
#define G_ 192
#define TILE_T 64
#define NTILES (T_ / TILE_T)   // 16
#define XGS 65                 // ring t-stride: 65%32=1 -> 2-way max (free)
#define KC 32                  // producer k-chunk
#define WS 194                 // w_s g-stride

typedef float f32x4 __attribute__((ext_vector_type(4)));
typedef unsigned long long u64;

// Fused GRU, 1 launch. Block = 1 batch row, 7 waves, 1 block/CU.
//   waves 0,1,2 : scan, one gate-DOT each; pointwise math REPLICATED in all
//                 three waves -> the r->n->z serial chain (3 hops/step in
//                 round 7, ~280 cyc each) collapses to ONE all-to-all hop.
//   waves 3..6  : register-tiled GEMM producers -> LDS ring.
// Slots are parity double-buffered {tag|value} b64: wave g cannot overwrite
// slot_g@t (at t+2) before both peers consumed slot_g@t, because their @t+1
// publishes (prerequisite of g's @t+2 dot) require reading slot_g@t.
__global__ __launch_bounds__(448, 2) void gru_fused(
    const float* __restrict__ lat, const float* __restrict__ hidden_init,
    const float* __restrict__ W_ih, const float* __restrict__ W_hh,
    const float* __restrict__ b_ih, const float* __restrict__ b_hh,
    const float* __restrict__ head_w, const float* __restrict__ head_b,
    float* __restrict__ out)
{
    __shared__ float xg_s[2][G_ * XGS];     // 99,840 B ring [slot][g*XGS+t]
    __shared__ float lat_s[D_ * TILE_T];    // 32,768 B [d][t]
    __shared__ float w_s[KC * WS];          // 24,832 B [kk][g]
    __shared__ float h_priv[3][H_];         // per-scan-wave private h copy
    __shared__ u64  slot[3][2][H_];         // [gate][parity][lane] {tag|val}
    __shared__ unsigned prod_done[2], cons_done[2], pbar;

    const int b    = blockIdx.x;
    const int tid  = threadIdx.x;
    const int lane = tid & 63;
    const int wid  = tid >> 6;

    if (tid < 2) { prod_done[tid] = 0u; cons_done[tid] = 0u; }
    if (tid == 2) pbar = 0u;
    if (tid < 192) { slot[tid >> 6][0][tid & 63] = 0ull;
                     slot[tid >> 6][1][tid & 63] = 0ull; }
    __syncthreads();   // only workgroup barrier (all 7 waves present)

    if (wid < 3) {
        // =============== scan: one gate-dot per wave, 1 hop/step ===============
        __builtin_amdgcn_s_setprio(1);
        const int j   = lane;
        const int row = wid * H_ + j;        // rows: r 0..63 | z 64..127 | n 128..191
        f32x4 w4[16];
        {
            const f32x4* W = (const f32x4*)(W_hh + (size_t)row * H_);
#pragma unroll
            for (int q = 0; q < 16; ++q) w4[q] = W[q];
        }
        asm volatile("" : "+v"(w4[0]), "+v"(w4[1]), "+v"(w4[2]), "+v"(w4[3]),
                          "+v"(w4[4]), "+v"(w4[5]), "+v"(w4[6]), "+v"(w4[7]),
                          "+v"(w4[8]), "+v"(w4[9]), "+v"(w4[10]), "+v"(w4[11]),
                          "+v"(w4[12]), "+v"(w4[13]), "+v"(w4[14]), "+v"(w4[15]));
        const float bias = b_hh[row];
        const float hw   = (wid == 0) ? head_w[j] : 0.f;
        const int o1 = (wid == 0) ? 1 : 0;
        const int o2 = (wid == 2) ? 1 : 2;
        float h = hidden_init[b * H_ + j];
        unsigned sg = 0;

        for (int k = 0; k < NTILES; ++k) {
            const int s = k & 1;
            const unsigned tgt = 4u * (unsigned)((k >> 1) + 1);
            while (__hip_atomic_load(&prod_done[s], __ATOMIC_ACQUIRE,
                                     __HIP_MEMORY_SCOPE_WORKGROUP) < tgt)
                __builtin_amdgcn_s_sleep(1);
            const float* xr_p = &xg_s[s][(size_t)j * XGS];
            const float* xz_p = &xg_s[s][(size_t)(H_ + j) * XGS];
            const float* xn_p = &xg_s[s][(size_t)(2 * H_ + j) * XGS];

#pragma unroll 2
            for (int t = 0; t < TILE_T; ++t, ++sg) {
                const int par = (int)(sg & 1u);
                // publish h to my private copy (within-wave DS order)
                h_priv[wid][j] = h;
                // x reads hide under the dot
                float xr = xr_p[t], xz = xz_p[t], xn = xn_p[t];
                const f32x4* h4 = (const f32x4*)h_priv[wid];
                float a0 = 0.f, a1 = 0.f, a2 = 0.f, a3 = 0.f;
#pragma unroll
                for (int q = 0; q < 16; ++q) {
                    f32x4 hv = h4[q];           // broadcast read
                    a0 = fmaf(w4[q].x, hv.x, a0); a1 = fmaf(w4[q].y, hv.y, a1);
                    a2 = fmaf(w4[q].z, hv.z, a2); a3 = fmaf(w4[q].w, hv.w, a3);
                }
                float a = ((a0 + a1) + (a2 + a3)) + bias;
                const unsigned want = sg + 1;

                // publish my dot, then poll the other two (single hop)
                u64 pk = ((u64)want << 32) | (u64)__builtin_bit_cast(unsigned, a);
                __hip_atomic_store(&slot[wid][par][j], pk, __ATOMIC_RELAXED,
                                   __HIP_MEMORY_SCOPE_WORKGROUP);
                u64 v1, v2;
                do {
                    v1 = __hip_atomic_load(&slot[o1][par][j], __ATOMIC_RELAXED,
                                           __HIP_MEMORY_SCOPE_WORKGROUP);
                    v2 = __hip_atomic_load(&slot[o2][par][j], __ATOMIC_RELAXED,
                                           __HIP_MEMORY_SCOPE_WORKGROUP);
                } while ((unsigned)(v1 >> 32) != want || (unsigned)(v2 >> 32) != want);
                float b1 = __builtin_bit_cast(float, (unsigned)v1);
                float b2 = __builtin_bit_cast(float, (unsigned)v2);

                float ar, az, an;
                if (wid == 0)      { ar = a;  az = b1; an = b2; }
                else if (wid == 1) { ar = b1; az = a;  an = b2; }
                else               { ar = b1; az = b2; an = a;  }

                // replicated pointwise (identical FP ops in all 3 waves)
                float r   = __builtin_amdgcn_rcpf(1.f + __expf(-(xr + ar)));
                float z   = __builtin_amdgcn_rcpf(1.f + __expf(-(xz + az)));
                float pre = xn + r * an;
                float n   = fmaf(-2.f, __builtin_amdgcn_rcpf(__expf(2.f * pre) + 1.f), 1.f);
                h = fmaf(z, h - n, n);           // (1-z)n + zh
            }
            if (lane == 0)   // each scan wave releases the tile (producers wait 3)
                __hip_atomic_fetch_add(&cons_done[s], 1u, __ATOMIC_RELEASE,
                                       __HIP_MEMORY_SCOPE_WORKGROUP);
        }

        if (wid == 0) {   // all waves hold identical final h
            out[B_ + b * H_ + j] = h;
            float v = h * hw;
#pragma unroll
            for (int off = 32; off > 0; off >>= 1) v += __shfl_down(v, off);
            if (lane == 0) out[b] = v + head_b[0];
        }
    } else {
        // ================= producers: register-tiled GEMM =================
        const int p  = tid - 192;        // 0..255
        const int tx = p & 7;            // t-sub: t = tx*8 + jj
        const int gy = p >> 3;           // g-sub: g = gy*6 + i
        const float* latb = lat + (size_t)b * (D_ * T_);
        unsigned phase = 0;

        auto psync = [&]() {
            if ((p & 63) == 0)
                __hip_atomic_fetch_add(&pbar, 1u, __ATOMIC_RELEASE,
                                       __HIP_MEMORY_SCOPE_WORKGROUP);
            ++phase;
            while (__hip_atomic_load(&pbar, __ATOMIC_ACQUIRE,
                                     __HIP_MEMORY_SCOPE_WORKGROUP) < 4u * phase) {}
        };

        float bias[6];
#pragma unroll
        for (int i = 0; i < 6; ++i) bias[i] = b_ih[gy * 6 + i];

        for (int k = 0; k < NTILES; ++k) {
            const int s = k & 1, m = k >> 1;
            if (m >= 1) {
                while (__hip_atomic_load(&cons_done[s], __ATOMIC_ACQUIRE,
                                         __HIP_MEMORY_SCOPE_WORKGROUP) < 3u * (unsigned)m)
                    __builtin_amdgcn_s_sleep(1);
            }
            psync();   // all producers past previous tile's lat_s/w_s

            // stage lat tile [d][t] (coalesced)
#pragma unroll
            for (int i = 0; i < 32; ++i) {
                int f = p + 256 * i;           // f = d*64 + t
                int d = f >> 6, t = f & 63;
                lat_s[f] = latb[(size_t)d * T_ + k * TILE_T + t];
            }

            float acc[8][6];
#pragma unroll
            for (int jj = 0; jj < 8; ++jj)
#pragma unroll
                for (int i = 0; i < 6; ++i) acc[jj][i] = 0.f;

            for (int kc = 0; kc < D_; kc += KC) {
                psync();   // lat_s staged / previous w_s consumed
#pragma unroll
                for (int i = 0; i < (G_ * KC) / 256; ++i) {   // 24/thread
                    int f = p + 256 * i;
                    int g = f >> 5, kk = f & 31;
                    w_s[kk * WS + g] = W_ih[(size_t)g * D_ + kc + kk];
                }
                psync();   // w_s ready
#pragma unroll 4
                for (int kk = 0; kk < KC; ++kk) {
                    f32x4 l0 = *(const f32x4*)&lat_s[(kc + kk) * 64 + tx * 8];
                    f32x4 l1 = *(const f32x4*)&lat_s[(kc + kk) * 64 + tx * 8 + 4];
                    float2 w0 = *(const float2*)&w_s[kk * WS + gy * 6];
                    float2 w1 = *(const float2*)&w_s[kk * WS + gy * 6 + 2];
                    float2 w2 = *(const float2*)&w_s[kk * WS + gy * 6 + 4];
                    float lv[8] = {l0.x, l0.y, l0.z, l0.w, l1.x, l1.y, l1.z, l1.w};
                    float wv[6] = {w0.x, w0.y, w1.x, w1.y, w2.x, w2.y};
#pragma unroll
                    for (int jj = 0; jj < 8; ++jj)
#pragma unroll
                        for (int i = 0; i < 6; ++i)
                            acc[jj][i] = fmaf(lv[jj], wv[i], acc[jj][i]);
                }
            }

            // write tile to ring slot
            float* xs = xg_s[s];
#pragma unroll
            for (int i = 0; i < 6; ++i)
#pragma unroll
                for (int jj = 0; jj < 8; ++jj)
                    xs[(size_t)(gy * 6 + i) * XGS + tx * 8 + jj] = acc[jj][i] + bias[i];

            if ((p & 63) == 0)
                __hip_atomic_fetch_add(&prod_done[s], 1u, __ATOMIC_RELEASE,
                                       __HIP_MEMORY_SCOPE_WORKGROUP);
        }
    }
}

extern "C" void kernel_launch(void* const* d_in, const int* in_sizes, int n_in,
                              void* d_out, int out_size, void* d_ws, size_t ws_size,
                              hipStream_t stream)
{
    const float* lat   = (const float*)d_in[0];
    const float* hid0  = (const float*)d_in[1];
    const float* W_ih  = (const float*)d_in[2];
    const float* W_hh  = (const float*)d_in[3];
    const float* b_ih  = (const float*)d_in[4];
    const float* b_hh  = (const float*)d_in[5];
    const float* headw = (const float*)d_in[6];
    const float* headb = (const float*)d_in[7];
    float* out = (float*)d_out;

    gru_fused<<<dim3(B_), dim3(448), 0, stream>>>(
        lat, hid0, W_ih, W_hh, b_ih, b_hh, headw, headb, out);
}